// Round 1
// baseline (594.011 us; speedup 1.0000x reference)
//
#include <hip/hip_runtime.h>
#include <hip/hip_bf16.h>

typedef __attribute__((ext_vector_type(8))) short bfrag8;   // 8 bf16 (4 VGPRs)
typedef __attribute__((ext_vector_type(4))) float f32x4;    // MFMA C/D

static constexpr int L_ = 2048;
static constexpr int H_ = 16;
static constexpr int D_ = 64;
static constexpr int ROWSTRIDE = H_ * D_;        // 1024 floats between consecutive l
static constexpr int BSTRIDE = L_ * H_ * D_;     // per-batch stride

__device__ __forceinline__ unsigned short f2bf(float f) {
  return __builtin_bit_cast(unsigned short, __float2bfloat16(f));
}

__global__ __launch_bounds__(256, 4)
void mha_fwd_kernel(const float* __restrict__ Qp, const float* __restrict__ Kp,
                    const float* __restrict__ Vp, float* __restrict__ Op) {
  const int bid = blockIdx.x;
  const int qt = 31 - (bid & 31);     // long blocks launch first (tail balance)
  const int bh = bid >> 5;
  const int h = bh & 15;
  const int b = bh >> 4;

  const int tid = threadIdx.x;
  const int w = tid >> 6;             // wave id, 0..3
  const int lane = tid & 63;
  const int g = lane >> 4;            // 16-lane group, 0..3
  const int c = lane & 15;

  __shared__ __align__(16) unsigned short Pb[4][16 * 64];   // per-wave P tile (bf16)
  unsigned short* P = Pb[w];

  const size_t base = (size_t)b * BSTRIDE + (size_t)h * D_;
  const float* Qb = Qp + base;
  const float* Kb = Kp + base;
  const float* Vb = Vp + base;
  float* Ob = Op + base;

  const int qr0 = qt * 64 + w * 16;   // this wave's first q row

  // ---- Q fragments, scale 1/sqrt(64)=0.125 folded in (exact pow2) ----
  bfrag8 qf[2];
  {
    const float* qp = Qb + (size_t)(qr0 + c) * ROWSTRIDE + g * 8;
#pragma unroll
    for (int s = 0; s < 2; ++s) {
      f32x4 a0 = *(const f32x4*)(qp + 32 * s);
      f32x4 a1 = *(const f32x4*)(qp + 32 * s + 4);
      bfrag8 f;
#pragma unroll
      for (int j = 0; j < 4; ++j) {
        f[j]     = (short)f2bf(a0[j] * 0.125f);
        f[j + 4] = (short)f2bf(a1[j] * 0.125f);
      }
      qf[s] = f;
    }
  }

  float m_i[4], l_i[4];
  f32x4 oacc[4];
#pragma unroll
  for (int i = 0; i < 4; ++i) {
    m_i[i] = -INFINITY;
    l_i[i] = 0.f;
    oacc[i][0] = oacc[i][1] = oacc[i][2] = oacc[i][3] = 0.f;
  }

  for (int t = 0; t <= qt; ++t) {
    const int kv0 = t * 64;
    const bool diag = (t == qt);
    const int kbmax = diag ? w : 3;

    // ---- S = Q K^T for 4 key blocks of 16 ----
    f32x4 sacc[4];
#pragma unroll
    for (int kb = 0; kb < 4; ++kb) {
      if (kb <= kbmax) {
        f32x4 acc;
        acc[0] = acc[1] = acc[2] = acc[3] = 0.f;
        const float* kp = Kb + (size_t)(kv0 + kb * 16 + c) * ROWSTRIDE + g * 8;
#pragma unroll
        for (int s = 0; s < 2; ++s) {
          f32x4 a0 = *(const f32x4*)(kp + 32 * s);
          f32x4 a1 = *(const f32x4*)(kp + 32 * s + 4);
          bfrag8 kf;
#pragma unroll
          for (int j = 0; j < 4; ++j) {
            kf[j]     = (short)f2bf(a0[j]);
            kf[j + 4] = (short)f2bf(a1[j]);
          }
          acc = __builtin_amdgcn_mfma_f32_16x16x32_bf16(qf[s], kf, acc, 0, 0, 0);
        }
        if (diag && kb == w) {          // triangular mask on the diagonal 16x16
#pragma unroll
          for (int i = 0; i < 4; ++i)
            if (c > 4 * g + i) acc[i] = -INFINITY;
        }
        sacc[kb] = acc;
      } else {                          // fully-masked block
        sacc[kb][0] = sacc[kb][1] = sacc[kb][2] = sacc[kb][3] = -INFINITY;
      }
    }

    // ---- online softmax (rows live in 16-lane groups; 4 rows per lane via regs) ----
    float tmax[4];
#pragma unroll
    for (int i = 0; i < 4; ++i)
      tmax[i] = fmaxf(fmaxf(sacc[0][i], sacc[1][i]), fmaxf(sacc[2][i], sacc[3][i]));
#pragma unroll
    for (int mk = 1; mk <= 8; mk <<= 1) {
#pragma unroll
      for (int i = 0; i < 4; ++i)
        tmax[i] = fmaxf(tmax[i], __shfl_xor(tmax[i], mk));
    }
    float rsum[4];
#pragma unroll
    for (int i = 0; i < 4; ++i) {
      const float mnew = fmaxf(m_i[i], tmax[i]);
      const float sc = __expf(m_i[i] - mnew);   // first tile: exp(-inf)=0
      m_i[i] = mnew;
      float rs = 0.f;
#pragma unroll
      for (int kb = 0; kb < 4; ++kb) {
        const float p = __expf(sacc[kb][i] - mnew);   // masked: exp(-inf)=0
        sacc[kb][i] = p;
        rs += p;
      }
      rsum[i] = rs;
      l_i[i] *= sc;
#pragma unroll
      for (int db = 0; db < 4; ++db) oacc[db][i] *= sc;
    }
#pragma unroll
    for (int mk = 1; mk <= 8; mk <<= 1) {
#pragma unroll
      for (int i = 0; i < 4; ++i) rsum[i] += __shfl_xor(rsum[i], mk);
    }
#pragma unroll
    for (int i = 0; i < 4; ++i) l_i[i] += rsum[i];

    // ---- write P (bf16) to LDS, XOR-swizzled 16B chunks to kill bank conflicts ----
#pragma unroll
    for (int kb = 0; kb < 4; ++kb) {
      const int col = kb * 16 + c;
      const int chunk = col >> 3;
      const int lo = col & 7;
#pragma unroll
      for (int i = 0; i < 4; ++i) {
        const int row = 4 * g + i;
        P[row * 64 + ((chunk ^ (row & 7)) * 8) + lo] = f2bf(sacc[kb][i]);
      }
    }
    asm volatile("s_waitcnt lgkmcnt(0)" ::: "memory");

    bfrag8 pa[2];
#pragma unroll
    for (int ks = 0; ks < 2; ++ks) {
      const int row = c;                               // A-frag row = lane&15
      const int chunk = (4 * ks + g) ^ (row & 7);
      pa[ks] = *(const bfrag8*)&P[row * 64 + chunk * 8];  // ds_read_b128
    }

    // ---- O += P V ----
#pragma unroll
    for (int ks = 0; ks < 2; ++ks) {
      const float* vp = Vb + (size_t)(kv0 + ks * 32 + g * 8) * ROWSTRIDE + c;
#pragma unroll
      for (int db = 0; db < 4; ++db) {
        bfrag8 vf;
#pragma unroll
        for (int j = 0; j < 8; ++j)
          vf[j] = (short)f2bf(vp[(size_t)j * ROWSTRIDE + db * 16]);
        oacc[db] = __builtin_amdgcn_mfma_f32_16x16x32_bf16(pa[ks], vf, oacc[db], 0, 0, 0);
      }
    }
  }

  // ---- epilogue: normalize and store ----
#pragma unroll
  for (int i = 0; i < 4; ++i) {
    const float inv = 1.f / l_i[i];
    const int q = qr0 + 4 * g + i;
    float* op = Ob + (size_t)q * ROWSTRIDE + c;
#pragma unroll
    for (int db = 0; db < 4; ++db)
      op[db * 16] = oacc[db][i] * inv;
  }
}

extern "C" void kernel_launch(void* const* d_in, const int* in_sizes, int n_in,
                              void* d_out, int out_size, void* d_ws, size_t ws_size,
                              hipStream_t stream) {
  const float* Q = (const float*)d_in[0];
  const float* K = (const float*)d_in[1];
  const float* V = (const float*)d_in[2];
  float* O = (float*)d_out;
  dim3 grid(4 * 16 * 32);   // B * H * (L/64)
  dim3 block(256);
  mha_fwd_kernel<<<grid, block, 0, stream>>>(Q, K, V, O);
}

// Round 2
// 300.214 us; speedup vs baseline: 1.9786x; 1.9786x over previous
//
#include <hip/hip_runtime.h>
#include <hip/hip_bf16.h>

typedef __attribute__((ext_vector_type(8))) short bfrag8;           // 8 bf16 (4 VGPRs)
typedef __attribute__((ext_vector_type(8))) unsigned short u16x8;   // 16B store unit
typedef __attribute__((ext_vector_type(4))) float f32x4;            // MFMA C/D

static constexpr int L_ = 2048;
static constexpr int H_ = 16;
static constexpr int D_ = 64;
static constexpr int ROWSTRIDE = H_ * D_;
static constexpr int BSTRIDE = L_ * H_ * D_;
static constexpr size_t NPH = (size_t)L_ * D_;          // elements per (b,h) plane
static constexpr size_t NTOT = (size_t)4 * H_ * L_ * D_; // 8388608 elements

__device__ __forceinline__ unsigned short f2bf(float f) {
  return __builtin_bit_cast(unsigned short, __float2bfloat16(f));
}

// ---------------------------------------------------------------------------
// Prep: f32 [B,L,H,D] -> bf16 Qb[B,H,L,D] (x0.125), Kb[B,H,L,D], Vt[B,H,D,L]
// ---------------------------------------------------------------------------
__global__ __launch_bounds__(256, 4)
void prep_kernel(const float* __restrict__ Q, const float* __restrict__ K,
                 const float* __restrict__ V, unsigned short* __restrict__ Qb,
                 unsigned short* __restrict__ Kb, unsigned short* __restrict__ Vt) {
  const int bid = blockIdx.x;
  const int lt = bid & 31;
  const int bh = bid >> 5;
  const int h = bh & 15;
  const int b = bh >> 4;
  const int l0 = lt * 64;
  const int t = threadIdx.x;
  const int lr = t >> 2;        // 0..63 row in tile
  const int dc = t & 3;         // 0..3, 16 dims each

  __shared__ __align__(16) unsigned short vt[64 * 64];  // swizzled 16B chunks

  const size_t src = ((size_t)(b * L_ + l0 + lr) * H_ + h) * D_ + dc * 16;
  const size_t dst = ((size_t)bh * L_ + l0 + lr) * D_ + dc * 16;

  {  // Q (scaled by 1/sqrt(D) = 0.125, exact pow2)
    f32x4 a = *(const f32x4*)(Q + src),     b4 = *(const f32x4*)(Q + src + 4),
          c4 = *(const f32x4*)(Q + src + 8), d4 = *(const f32x4*)(Q + src + 12);
    u16x8 o0, o1;
#pragma unroll
    for (int j = 0; j < 4; ++j) {
      o0[j] = f2bf(a[j] * 0.125f);  o0[j + 4] = f2bf(b4[j] * 0.125f);
      o1[j] = f2bf(c4[j] * 0.125f); o1[j + 4] = f2bf(d4[j] * 0.125f);
    }
    *(u16x8*)(Qb + dst) = o0;
    *(u16x8*)(Qb + dst + 8) = o1;
  }
  {  // K
    f32x4 a = *(const f32x4*)(K + src),     b4 = *(const f32x4*)(K + src + 4),
          c4 = *(const f32x4*)(K + src + 8), d4 = *(const f32x4*)(K + src + 12);
    u16x8 o0, o1;
#pragma unroll
    for (int j = 0; j < 4; ++j) {
      o0[j] = f2bf(a[j]);  o0[j + 4] = f2bf(b4[j]);
      o1[j] = f2bf(c4[j]); o1[j + 4] = f2bf(d4[j]);
    }
    *(u16x8*)(Kb + dst) = o0;
    *(u16x8*)(Kb + dst + 8) = o1;
  }
  {  // V -> LDS (swizzled chunks), then transpose out
    f32x4 a = *(const f32x4*)(V + src),     b4 = *(const f32x4*)(V + src + 4),
          c4 = *(const f32x4*)(V + src + 8), d4 = *(const f32x4*)(V + src + 12);
    u16x8 o0, o1;
#pragma unroll
    for (int j = 0; j < 4; ++j) {
      o0[j] = f2bf(a[j]);  o0[j + 4] = f2bf(b4[j]);
      o1[j] = f2bf(c4[j]); o1[j + 4] = f2bf(d4[j]);
    }
    const int r7 = (lr + (lr >> 3)) & 7;
    *(u16x8*)&vt[lr * 64 + (((dc * 2) ^ r7) * 8)] = o0;
    *(u16x8*)&vt[lr * 64 + (((dc * 2 + 1) ^ r7) * 8)] = o1;
  }
  __syncthreads();
  {  // transpose out: thread owns dim d, 16 consecutive l
    const int d = t >> 2;       // 0..63
    const int lc = t & 3;       // 0..3
    const int ch = d >> 3, dl = d & 7;
    u16x8 o0, o1;
#pragma unroll
    for (int i = 0; i < 8; ++i) {
      const int r0 = lc * 16 + i;
      const int r1 = lc * 16 + 8 + i;
      o0[i] = vt[r0 * 64 + ((ch ^ ((r0 + (r0 >> 3)) & 7)) * 8) + dl];
      o1[i] = vt[r1 * 64 + ((ch ^ ((r1 + (r1 >> 3)) & 7)) * 8) + dl];
    }
    const size_t vd = ((size_t)bh * D_ + d) * L_ + l0 + lc * 16;
    *(u16x8*)(Vt + vd) = o0;
    *(u16x8*)(Vt + vd + 8) = o1;
  }
}

// ---------------------------------------------------------------------------
// Flash attention on bf16 planes; 4 independent waves x 16 q-rows per block
// ---------------------------------------------------------------------------
__global__ __launch_bounds__(256, 4)
void mha_fwd_bf16(const unsigned short* __restrict__ Qb,
                  const unsigned short* __restrict__ Kb,
                  const unsigned short* __restrict__ Vt,
                  float* __restrict__ Op) {
  const int bid = blockIdx.x;
  const int qt = 31 - (bid >> 6);   // long blocks first
  const int bh = bid & 63;
  const int h = bh & 15;
  const int b = bh >> 4;

  const int tid = threadIdx.x;
  const int w = tid >> 6;
  const int lane = tid & 63;
  const int g = lane >> 4;
  const int c = lane & 15;

  __shared__ __align__(16) unsigned short Pb[4][16 * 64];
  unsigned short* P = Pb[w];

  const unsigned short* Qh = Qb + (size_t)bh * NPH;
  const unsigned short* Kh = Kb + (size_t)bh * NPH;
  const unsigned short* Vh = Vt + (size_t)bh * NPH;
  float* Ob = Op + (size_t)b * BSTRIDE + (size_t)h * D_;

  const int qr0 = qt * 64 + w * 16;

  bfrag8 qf[2];
  qf[0] = *(const bfrag8*)(Qh + (size_t)(qr0 + c) * D_ + g * 8);
  qf[1] = *(const bfrag8*)(Qh + (size_t)(qr0 + c) * D_ + 32 + g * 8);

  float m_i[4], l_i[4];
  f32x4 oacc[4];
#pragma unroll
  for (int i = 0; i < 4; ++i) {
    m_i[i] = -INFINITY;
    l_i[i] = 0.f;
    oacc[i][0] = oacc[i][1] = oacc[i][2] = oacc[i][3] = 0.f;
  }

  for (int t = 0; t <= qt; ++t) {
    const int kv0 = t * 64;

    // ---- K fragments: 8 x 16B vector loads ----
    bfrag8 kf[4][2];
#pragma unroll
    for (int kb = 0; kb < 4; ++kb)
#pragma unroll
      for (int s = 0; s < 2; ++s)
        kf[kb][s] = *(const bfrag8*)(Kh + (size_t)(kv0 + kb * 16 + c) * D_ + s * 32 + g * 8);

    // ---- S = Q K^T ----
    f32x4 sacc[4];
#pragma unroll
    for (int kb = 0; kb < 4; ++kb) {
      f32x4 acc;
      acc[0] = acc[1] = acc[2] = acc[3] = 0.f;
#pragma unroll
      for (int s = 0; s < 2; ++s)
        acc = __builtin_amdgcn_mfma_f32_16x16x32_bf16(qf[s], kf[kb][s], acc, 0, 0, 0);
      sacc[kb] = acc;
    }

    // ---- V fragments: issue early so softmax VALU hides their latency ----
    bfrag8 vf[2][4];
#pragma unroll
    for (int ks = 0; ks < 2; ++ks)
#pragma unroll
      for (int db = 0; db < 4; ++db)
        vf[ks][db] = *(const bfrag8*)(Vh + (size_t)(db * 16 + c) * L_ + kv0 + ks * 32 + g * 8);

    // ---- causal mask on the diagonal tile ----
    if (t == qt) {
#pragma unroll
      for (int kb = 0; kb < 4; ++kb) {
        if (kb == w) {
#pragma unroll
          for (int i = 0; i < 4; ++i)
            if (c > 4 * g + i) sacc[kb][i] = -INFINITY;
        } else if (kb > w) {
#pragma unroll
          for (int i = 0; i < 4; ++i) sacc[kb][i] = -INFINITY;
        }
      }
    }

    // ---- online softmax ----
    float tmax[4];
#pragma unroll
    for (int i = 0; i < 4; ++i)
      tmax[i] = fmaxf(fmaxf(sacc[0][i], sacc[1][i]), fmaxf(sacc[2][i], sacc[3][i]));
#pragma unroll
    for (int mk = 1; mk <= 8; mk <<= 1) {
#pragma unroll
      for (int i = 0; i < 4; ++i)
        tmax[i] = fmaxf(tmax[i], __shfl_xor(tmax[i], mk));
    }
    float rsum[4];
#pragma unroll
    for (int i = 0; i < 4; ++i) {
      const float mnew = fmaxf(m_i[i], tmax[i]);
      const float sc = __expf(m_i[i] - mnew);
      m_i[i] = mnew;
      float rs = 0.f;
#pragma unroll
      for (int kb = 0; kb < 4; ++kb) {
        const float p = __expf(sacc[kb][i] - mnew);
        sacc[kb][i] = p;
        rs += p;
      }
      rsum[i] = rs;
      l_i[i] *= sc;
#pragma unroll
      for (int db = 0; db < 4; ++db) oacc[db][i] *= sc;
    }
#pragma unroll
    for (int mk = 1; mk <= 8; mk <<= 1) {
#pragma unroll
      for (int i = 0; i < 4; ++i) rsum[i] += __shfl_xor(rsum[i], mk);
    }
#pragma unroll
    for (int i = 0; i < 4; ++i) l_i[i] += rsum[i];

    // ---- P (bf16) -> LDS, XOR-swizzled; read back as A fragments ----
#pragma unroll
    for (int kb = 0; kb < 4; ++kb) {
      const int col = kb * 16 + c;
      const int chunk = col >> 3;
      const int lo = col & 7;
#pragma unroll
      for (int i = 0; i < 4; ++i) {
        const int row = 4 * g + i;
        P[row * 64 + ((chunk ^ (row & 7)) * 8) + lo] = f2bf(sacc[kb][i]);
      }
    }
    asm volatile("s_waitcnt lgkmcnt(0)" ::: "memory");

    bfrag8 pa[2];
#pragma unroll
    for (int ks = 0; ks < 2; ++ks) {
      const int row = c;
      const int chunk = (4 * ks + g) ^ (row & 7);
      pa[ks] = *(const bfrag8*)&P[row * 64 + chunk * 8];
    }

    // ---- O += P V ----
#pragma unroll
    for (int ks = 0; ks < 2; ++ks)
#pragma unroll
      for (int db = 0; db < 4; ++db)
        oacc[db] = __builtin_amdgcn_mfma_f32_16x16x32_bf16(pa[ks], vf[ks][db], oacc[db], 0, 0, 0);
  }

  // ---- epilogue ----
#pragma unroll
  for (int i = 0; i < 4; ++i) {
    const float inv = 1.f / l_i[i];
    const int q = qr0 + 4 * g + i;
    float* op = Ob + (size_t)q * ROWSTRIDE + c;
#pragma unroll
    for (int db = 0; db < 4; ++db)
      op[db * 16] = oacc[db][i] * inv;
  }
}

// ---------------------------------------------------------------------------
// Fallback (round-1 kernel) if workspace is too small for the bf16 planes
// ---------------------------------------------------------------------------
__global__ __launch_bounds__(256, 4)
void mha_fwd_f32(const float* __restrict__ Qp, const float* __restrict__ Kp,
                 const float* __restrict__ Vp, float* __restrict__ Op) {
  const int bid = blockIdx.x;
  const int qt = 31 - (bid & 31);
  const int bh = bid >> 5;
  const int h = bh & 15;
  const int b = bh >> 4;
  const int tid = threadIdx.x;
  const int w = tid >> 6;
  const int lane = tid & 63;
  const int g = lane >> 4;
  const int c = lane & 15;

  __shared__ __align__(16) unsigned short Pb[4][16 * 64];
  unsigned short* P = Pb[w];

  const size_t base = (size_t)b * BSTRIDE + (size_t)h * D_;
  const float* Qb = Qp + base;
  const float* Kb = Kp + base;
  const float* Vb = Vp + base;
  float* Ob = Op + base;
  const int qr0 = qt * 64 + w * 16;

  bfrag8 qf[2];
  {
    const float* qp = Qb + (size_t)(qr0 + c) * ROWSTRIDE + g * 8;
#pragma unroll
    for (int s = 0; s < 2; ++s) {
      f32x4 a0 = *(const f32x4*)(qp + 32 * s);
      f32x4 a1 = *(const f32x4*)(qp + 32 * s + 4);
      bfrag8 f;
#pragma unroll
      for (int j = 0; j < 4; ++j) {
        f[j] = (short)f2bf(a0[j] * 0.125f);
        f[j + 4] = (short)f2bf(a1[j] * 0.125f);
      }
      qf[s] = f;
    }
  }
  float m_i[4], l_i[4];
  f32x4 oacc[4];
#pragma unroll
  for (int i = 0; i < 4; ++i) {
    m_i[i] = -INFINITY; l_i[i] = 0.f;
    oacc[i][0] = oacc[i][1] = oacc[i][2] = oacc[i][3] = 0.f;
  }
  for (int t = 0; t <= qt; ++t) {
    const int kv0 = t * 64;
    const bool diag = (t == qt);
    const int kbmax = diag ? w : 3;
    f32x4 sacc[4];
#pragma unroll
    for (int kb = 0; kb < 4; ++kb) {
      if (kb <= kbmax) {
        f32x4 acc; acc[0] = acc[1] = acc[2] = acc[3] = 0.f;
        const float* kp = Kb + (size_t)(kv0 + kb * 16 + c) * ROWSTRIDE + g * 8;
#pragma unroll
        for (int s = 0; s < 2; ++s) {
          f32x4 a0 = *(const f32x4*)(kp + 32 * s);
          f32x4 a1 = *(const f32x4*)(kp + 32 * s + 4);
          bfrag8 kf;
#pragma unroll
          for (int j = 0; j < 4; ++j) {
            kf[j] = (short)f2bf(a0[j]);
            kf[j + 4] = (short)f2bf(a1[j]);
          }
          acc = __builtin_amdgcn_mfma_f32_16x16x32_bf16(qf[s], kf, acc, 0, 0, 0);
        }
        if (diag && kb == w) {
#pragma unroll
          for (int i = 0; i < 4; ++i)
            if (c > 4 * g + i) acc[i] = -INFINITY;
        }
        sacc[kb] = acc;
      } else {
        sacc[kb][0] = sacc[kb][1] = sacc[kb][2] = sacc[kb][3] = -INFINITY;
      }
    }
    float tmax[4];
#pragma unroll
    for (int i = 0; i < 4; ++i)
      tmax[i] = fmaxf(fmaxf(sacc[0][i], sacc[1][i]), fmaxf(sacc[2][i], sacc[3][i]));
#pragma unroll
    for (int mk = 1; mk <= 8; mk <<= 1)
#pragma unroll
      for (int i = 0; i < 4; ++i) tmax[i] = fmaxf(tmax[i], __shfl_xor(tmax[i], mk));
    float rsum[4];
#pragma unroll
    for (int i = 0; i < 4; ++i) {
      const float mnew = fmaxf(m_i[i], tmax[i]);
      const float sc = __expf(m_i[i] - mnew);
      m_i[i] = mnew;
      float rs = 0.f;
#pragma unroll
      for (int kb = 0; kb < 4; ++kb) {
        const float p = __expf(sacc[kb][i] - mnew);
        sacc[kb][i] = p; rs += p;
      }
      rsum[i] = rs; l_i[i] *= sc;
#pragma unroll
      for (int db = 0; db < 4; ++db) oacc[db][i] *= sc;
    }
#pragma unroll
    for (int mk = 1; mk <= 8; mk <<= 1)
#pragma unroll
      for (int i = 0; i < 4; ++i) rsum[i] += __shfl_xor(rsum[i], mk);
#pragma unroll
    for (int i = 0; i < 4; ++i) l_i[i] += rsum[i];
#pragma unroll
    for (int kb = 0; kb < 4; ++kb) {
      const int col = kb * 16 + c;
      const int chunk = col >> 3;
      const int lo = col & 7;
#pragma unroll
      for (int i = 0; i < 4; ++i) {
        const int row = 4 * g + i;
        P[row * 64 + ((chunk ^ (row & 7)) * 8) + lo] = f2bf(sacc[kb][i]);
      }
    }
    asm volatile("s_waitcnt lgkmcnt(0)" ::: "memory");
    bfrag8 pa[2];
#pragma unroll
    for (int ks = 0; ks < 2; ++ks) {
      const int row = c;
      const int chunk = (4 * ks + g) ^ (row & 7);
      pa[ks] = *(const bfrag8*)&P[row * 64 + chunk * 8];
    }
#pragma unroll
    for (int ks = 0; ks < 2; ++ks) {
      const float* vp = Vb + (size_t)(kv0 + ks * 32 + g * 8) * ROWSTRIDE + c;
#pragma unroll
      for (int db = 0; db < 4; ++db) {
        bfrag8 vf;
#pragma unroll
        for (int j = 0; j < 8; ++j)
          vf[j] = (short)f2bf(vp[(size_t)j * ROWSTRIDE + db * 16]);
        oacc[db] = __builtin_amdgcn_mfma_f32_16x16x32_bf16(pa[ks], vf, oacc[db], 0, 0, 0);
      }
    }
  }
#pragma unroll
  for (int i = 0; i < 4; ++i) {
    const float inv = 1.f / l_i[i];
    const int q = qr0 + 4 * g + i;
    float* op = Ob + (size_t)q * ROWSTRIDE + c;
#pragma unroll
    for (int db = 0; db < 4; ++db)
      op[db * 16] = oacc[db][i] * inv;
  }
}

extern "C" void kernel_launch(void* const* d_in, const int* in_sizes, int n_in,
                              void* d_out, int out_size, void* d_ws, size_t ws_size,
                              hipStream_t stream) {
  const float* Q = (const float*)d_in[0];
  const float* K = (const float*)d_in[1];
  const float* V = (const float*)d_in[2];
  float* O = (float*)d_out;

  const size_t need = 3 * NTOT * sizeof(unsigned short);
  if (ws_size >= need) {
    unsigned short* Qb = (unsigned short*)d_ws;
    unsigned short* Kb = Qb + NTOT;
    unsigned short* Vt = Kb + NTOT;
    prep_kernel<<<dim3(2048), dim3(256), 0, stream>>>(Q, K, V, Qb, Kb, Vt);
    mha_fwd_bf16<<<dim3(2048), dim3(256), 0, stream>>>(Qb, Kb, Vt, O);
  } else {
    mha_fwd_f32<<<dim3(2048), dim3(256), 0, stream>>>(Q, K, V, O);
  }
}

// Round 3
// 156.119 us; speedup vs baseline: 3.8049x; 1.9230x over previous
//
#include <hip/hip_runtime.h>
#include <hip/hip_bf16.h>

typedef __attribute__((ext_vector_type(8))) short bfrag8;           // 8 bf16
typedef __attribute__((ext_vector_type(8))) unsigned short u16x8;
typedef __attribute__((ext_vector_type(4))) float f32x4;
typedef __attribute__((ext_vector_type(16))) float f32x16;          // 32x32 MFMA C/D
typedef __attribute__((ext_vector_type(4))) unsigned int u32x4;

static constexpr int L_ = 2048;
static constexpr int H_ = 16;
static constexpr int D_ = 64;
static constexpr int ROWSTRIDE = H_ * D_;
static constexpr int BSTRIDE = L_ * H_ * D_;
static constexpr size_t NPH = (size_t)L_ * D_;
static constexpr size_t NTOT = (size_t)4 * H_ * L_ * D_;

__device__ __forceinline__ unsigned short f2bf(float f) {
  return __builtin_bit_cast(unsigned short, __float2bfloat16(f));
}
__device__ __forceinline__ unsigned int pack2(float lo, float hi) {
  return (unsigned int)f2bf(lo) | ((unsigned int)f2bf(hi) << 16);
}

// ---------------------------------------------------------------------------
// Prep: f32 [B,L,H,D] -> bf16 Qb[B,H,L,D] (x0.125), Kb[B,H,L,D], Vt[B,H,D,L]
// ---------------------------------------------------------------------------
__global__ __launch_bounds__(256, 4)
void prep_kernel(const float* __restrict__ Q, const float* __restrict__ K,
                 const float* __restrict__ V, unsigned short* __restrict__ Qb,
                 unsigned short* __restrict__ Kb, unsigned short* __restrict__ Vt) {
  const int bid = blockIdx.x;
  const int lt = bid & 31;
  const int bh = bid >> 5;
  const int h = bh & 15;
  const int b = bh >> 4;
  const int l0 = lt * 64;
  const int t = threadIdx.x;
  const int lr = t >> 2;
  const int dc = t & 3;

  __shared__ __align__(16) unsigned short vt[64 * 64];

  const size_t src = ((size_t)(b * L_ + l0 + lr) * H_ + h) * D_ + dc * 16;
  const size_t dst = ((size_t)bh * L_ + l0 + lr) * D_ + dc * 16;

  {
    f32x4 a = *(const f32x4*)(Q + src),     b4 = *(const f32x4*)(Q + src + 4),
          c4 = *(const f32x4*)(Q + src + 8), d4 = *(const f32x4*)(Q + src + 12);
    u16x8 o0, o1;
#pragma unroll
    for (int j = 0; j < 4; ++j) {
      o0[j] = f2bf(a[j] * 0.125f);  o0[j + 4] = f2bf(b4[j] * 0.125f);
      o1[j] = f2bf(c4[j] * 0.125f); o1[j + 4] = f2bf(d4[j] * 0.125f);
    }
    *(u16x8*)(Qb + dst) = o0;
    *(u16x8*)(Qb + dst + 8) = o1;
  }
  {
    f32x4 a = *(const f32x4*)(K + src),     b4 = *(const f32x4*)(K + src + 4),
          c4 = *(const f32x4*)(K + src + 8), d4 = *(const f32x4*)(K + src + 12);
    u16x8 o0, o1;
#pragma unroll
    for (int j = 0; j < 4; ++j) {
      o0[j] = f2bf(a[j]);  o0[j + 4] = f2bf(b4[j]);
      o1[j] = f2bf(c4[j]); o1[j + 4] = f2bf(d4[j]);
    }
    *(u16x8*)(Kb + dst) = o0;
    *(u16x8*)(Kb + dst + 8) = o1;
  }
  {
    f32x4 a = *(const f32x4*)(V + src),     b4 = *(const f32x4*)(V + src + 4),
          c4 = *(const f32x4*)(V + src + 8), d4 = *(const f32x4*)(V + src + 12);
    u16x8 o0, o1;
#pragma unroll
    for (int j = 0; j < 4; ++j) {
      o0[j] = f2bf(a[j]);  o0[j + 4] = f2bf(b4[j]);
      o1[j] = f2bf(c4[j]); o1[j + 4] = f2bf(d4[j]);
    }
    const int r7 = (lr + (lr >> 3)) & 7;
    *(u16x8*)&vt[lr * 64 + (((dc * 2) ^ r7) * 8)] = o0;
    *(u16x8*)&vt[lr * 64 + (((dc * 2 + 1) ^ r7) * 8)] = o1;
  }
  __syncthreads();
  {
    const int d = t >> 2;
    const int lc = t & 3;
    const int ch = d >> 3, dl = d & 7;
    u16x8 o0, o1;
#pragma unroll
    for (int i = 0; i < 8; ++i) {
      const int r0 = lc * 16 + i;
      const int r1 = lc * 16 + 8 + i;
      o0[i] = vt[r0 * 64 + ((ch ^ ((r0 + (r0 >> 3)) & 7)) * 8) + dl];
      o1[i] = vt[r1 * 64 + ((ch ^ ((r1 + (r1 >> 3)) & 7)) * 8) + dl];
    }
    const size_t vd = ((size_t)bh * D_ + d) * L_ + l0 + lc * 16;
    *(u16x8*)(Vt + vd) = o0;
    *(u16x8*)(Vt + vd + 8) = o1;
  }
}

// ---------------------------------------------------------------------------
// Swapped-operand flash attention: 1 wave per block, 32 q-rows per wave.
// S^T = mfma(K, Q): lane holds S[q=lane&31][k over regs]; softmax in-register.
// O^T = mfma(V^T, P^T): lane holds O[q=lane&31][d over regs] -> uniform 1/l.
// ---------------------------------------------------------------------------
__global__ __launch_bounds__(64, 3)
void mha_fwd_sw(const unsigned short* __restrict__ Qb,
                const unsigned short* __restrict__ Kb,
                const unsigned short* __restrict__ Vt,
                float* __restrict__ Op) {
  const int bid = blockIdx.x;
  const int plane = bid & 63;               // b*16 + h
  const int qti = 63 - (bid >> 6);          // longest first
  const int h = plane & 15;
  const int b = plane >> 4;

  const int lane = threadIdx.x;             // 0..63
  const int q = lane & 31;
  const int hi = lane >> 5;

  const unsigned short* Qh = Qb + (size_t)plane * NPH;
  const unsigned short* Kh = Kb + (size_t)plane * NPH;
  const unsigned short* Vh = Vt + (size_t)plane * NPH;
  float* Ob = Op + (size_t)b * BSTRIDE + (size_t)h * D_;

  const int qr0 = qti * 32;

  // Q B-frags: lane holds Q[qr0+q][16s + 8hi + j], j=0..7
  bfrag8 qB[4];
#pragma unroll
  for (int s = 0; s < 4; ++s)
    qB[s] = *(const bfrag8*)(Qh + (q + qr0) * D_ + 16 * s + 8 * hi);

  float m = -INFINITY;
  float lp = 0.f;                            // own-half row-sum partial
  f32x16 o0 = {};                            // O[q][d=crow+0..31]
  f32x16 o1 = {};                            // O[q][d=crow+32..63]

  for (int t = 0; t <= qti; ++t) {
    const int kv0 = t * 32;

    // K A-frags: lane holds K[kv0 + (lane&31)][16s + 8hi + j]
    bfrag8 kA[4];
#pragma unroll
    for (int s = 0; s < 4; ++s)
      kA[s] = *(const bfrag8*)(Kh + (kv0 + q) * D_ + 16 * s + 8 * hi);

    // V A-frags (issue early; softmax hides their latency):
    // lane holds V[kv0 + 16ks + 8hi + j][32dh + (lane&31)]
    bfrag8 vA[2][2];
#pragma unroll
    for (int ks = 0; ks < 2; ++ks)
#pragma unroll
      for (int dh = 0; dh < 2; ++dh)
        vA[ks][dh] = *(const bfrag8*)(Vh + (32 * dh + q) * L_ + kv0 + 16 * ks + 8 * hi);

    // S^T tile: lane q = lane&31, k = crow(reg,hi) = (r&3)+8*(r>>2)+4*hi
    f32x16 sacc = {};
#pragma unroll
    for (int s = 0; s < 4; ++s)
      sacc = __builtin_amdgcn_mfma_f32_32x32x16_bf16(kA[s], qB[s], sacc, 0, 0, 0);

    // causal mask (diagonal tile only; kv0 == qr0 there)
    if (t == qti) {
#pragma unroll
      for (int r = 0; r < 16; ++r) {
        const int crow = (r & 3) + 8 * (r >> 2) + 4 * hi;
        if (crow > q) sacc[r] = -INFINITY;
      }
    }

    // row max: in-lane tree + one cross-half exchange
    float tm = fmaxf(sacc[0], sacc[1]);
#pragma unroll
    for (int r = 2; r < 16; ++r) tm = fmaxf(tm, sacc[r]);
    tm = fmaxf(tm, __shfl_xor(tm, 32));

    const float mnew = fmaxf(m, tm);
    const float alpha = __expf(m - mnew);    // first tile: exp(-inf)=0
    m = mnew;

    float p[16];
    float rs = 0.f;
#pragma unroll
    for (int r = 0; r < 16; ++r) {
      p[r] = __expf(sacc[r] - mnew);         // masked: exp(-inf)=0
      rs += p[r];
    }
    lp = lp * alpha + rs;
    o0 *= alpha;
    o1 *= alpha;

    // ---- build P^T B-frags in-register (cvt-pack + cross-half exchange) ----
    unsigned int a0 = pack2(p[0],  p[1]),  a1 = pack2(p[2],  p[3]);
    unsigned int a2 = pack2(p[4],  p[5]),  a3 = pack2(p[6],  p[7]);
    unsigned int a4 = pack2(p[8],  p[9]),  a5 = pack2(p[10], p[11]);
    unsigned int a6 = pack2(p[12], p[13]), a7 = pack2(p[14], p[15]);

    const unsigned int x0 = __shfl_xor(hi ? a0 : a2, 32);
    const unsigned int x1 = __shfl_xor(hi ? a1 : a3, 32);
    const unsigned int x2 = __shfl_xor(hi ? a4 : a6, 32);
    const unsigned int x3 = __shfl_xor(hi ? a5 : a7, 32);

    // pb0: k = 16*0 + 8hi + j ; pb1: k = 16*1 + 8hi + j  (for q = lane&31)
    u32x4 w0, w1;
    w0[0] = hi ? x0 : a0;  w0[1] = hi ? x1 : a1;
    w0[2] = hi ? a2 : x0;  w0[3] = hi ? a3 : x1;
    w1[0] = hi ? x2 : a4;  w1[1] = hi ? x3 : a5;
    w1[2] = hi ? a6 : x2;  w1[3] = hi ? a7 : x3;
    const bfrag8 pb0 = __builtin_bit_cast(bfrag8, w0);
    const bfrag8 pb1 = __builtin_bit_cast(bfrag8, w1);

    // ---- O^T += V^T P^T ----
    o0 = __builtin_amdgcn_mfma_f32_32x32x16_bf16(vA[0][0], pb0, o0, 0, 0, 0);
    o0 = __builtin_amdgcn_mfma_f32_32x32x16_bf16(vA[1][0], pb1, o0, 0, 0, 0);
    o1 = __builtin_amdgcn_mfma_f32_32x32x16_bf16(vA[0][1], pb0, o1, 0, 0, 0);
    o1 = __builtin_amdgcn_mfma_f32_32x32x16_bf16(vA[1][1], pb1, o1, 0, 0, 0);
  }

  // ---- epilogue: combine row-sum halves, normalize, store ----
  lp += __shfl_xor(lp, 32);
  const float inv = 1.f / lp;

  float* orow = Ob + (size_t)(qr0 + q) * ROWSTRIDE;
#pragma unroll
  for (int r2 = 0; r2 < 4; ++r2) {
    f32x4 s0, s1;
#pragma unroll
    for (int j = 0; j < 4; ++j) {
      s0[j] = o0[4 * r2 + j] * inv;
      s1[j] = o1[4 * r2 + j] * inv;
    }
    *(f32x4*)(orow + 8 * r2 + 4 * hi) = s0;         // d = crow(reg,hi)
    *(f32x4*)(orow + 32 + 8 * r2 + 4 * hi) = s1;    // d = 32 + crow(reg,hi)
  }
}

// ---------------------------------------------------------------------------
// Fallback if workspace too small (round-1 style, f32 direct)
// ---------------------------------------------------------------------------
__global__ __launch_bounds__(256, 4)
void mha_fwd_f32(const float* __restrict__ Qp, const float* __restrict__ Kp,
                 const float* __restrict__ Vp, float* __restrict__ Op) {
  const int bid = blockIdx.x;
  const int qt = 31 - (bid & 31);
  const int bh = bid >> 5;
  const int h = bh & 15;
  const int b = bh >> 4;
  const int tid = threadIdx.x;
  const int w = tid >> 6;
  const int lane = tid & 63;
  const int g = lane >> 4;
  const int c = lane & 15;

  __shared__ __align__(16) unsigned short Pb[4][16 * 64];
  unsigned short* P = Pb[w];

  const size_t base = (size_t)b * BSTRIDE + (size_t)h * D_;
  const float* Qb = Qp + base;
  const float* Kb = Kp + base;
  const float* Vb = Vp + base;
  float* Ob = Op + base;
  const int qr0 = qt * 64 + w * 16;

  bfrag8 qf[2];
  {
    const float* qp = Qb + (size_t)(qr0 + c) * ROWSTRIDE + g * 8;
#pragma unroll
    for (int s = 0; s < 2; ++s) {
      f32x4 a0 = *(const f32x4*)(qp + 32 * s);
      f32x4 a1 = *(const f32x4*)(qp + 32 * s + 4);
      bfrag8 f;
#pragma unroll
      for (int j = 0; j < 4; ++j) {
        f[j] = (short)f2bf(a0[j] * 0.125f);
        f[j + 4] = (short)f2bf(a1[j] * 0.125f);
      }
      qf[s] = f;
    }
  }
  float m_i[4], l_i[4];
  f32x4 oacc[4];
#pragma unroll
  for (int i = 0; i < 4; ++i) {
    m_i[i] = -INFINITY; l_i[i] = 0.f;
    oacc[i][0] = oacc[i][1] = oacc[i][2] = oacc[i][3] = 0.f;
  }
  for (int t = 0; t <= qt; ++t) {
    const int kv0 = t * 64;
    const bool diag = (t == qt);
    const int kbmax = diag ? w : 3;
    f32x4 sacc[4];
#pragma unroll
    for (int kb = 0; kb < 4; ++kb) {
      if (kb <= kbmax) {
        f32x4 acc; acc[0] = acc[1] = acc[2] = acc[3] = 0.f;
        const float* kp = Kb + (size_t)(kv0 + kb * 16 + c) * ROWSTRIDE + g * 8;
#pragma unroll
        for (int s = 0; s < 2; ++s) {
          f32x4 a0 = *(const f32x4*)(kp + 32 * s);
          f32x4 a1 = *(const f32x4*)(kp + 32 * s + 4);
          bfrag8 kf;
#pragma unroll
          for (int j = 0; j < 4; ++j) {
            kf[j] = (short)f2bf(a0[j]);
            kf[j + 4] = (short)f2bf(a1[j]);
          }
          acc = __builtin_amdgcn_mfma_f32_16x16x32_bf16(qf[s], kf, acc, 0, 0, 0);
        }
        if (diag && kb == w) {
#pragma unroll
          for (int i = 0; i < 4; ++i)
            if (c > 4 * g + i) acc[i] = -INFINITY;
        }
        sacc[kb] = acc;
      } else {
        sacc[kb][0] = sacc[kb][1] = sacc[kb][2] = sacc[kb][3] = -INFINITY;
      }
    }
    float tmax[4];
#pragma unroll
    for (int i = 0; i < 4; ++i)
      tmax[i] = fmaxf(fmaxf(sacc[0][i], sacc[1][i]), fmaxf(sacc[2][i], sacc[3][i]));
#pragma unroll
    for (int mk = 1; mk <= 8; mk <<= 1)
#pragma unroll
      for (int i = 0; i < 4; ++i) tmax[i] = fmaxf(tmax[i], __shfl_xor(tmax[i], mk));
    float rsum[4];
#pragma unroll
    for (int i = 0; i < 4; ++i) {
      const float mnew = fmaxf(m_i[i], tmax[i]);
      const float sc = __expf(m_i[i] - mnew);
      m_i[i] = mnew;
      float rs = 0.f;
#pragma unroll
      for (int kb = 0; kb < 4; ++kb) {
        const float p = __expf(sacc[kb][i] - mnew);
        sacc[kb][i] = p; rs += p;
      }
      rsum[i] = rs; l_i[i] *= sc;
#pragma unroll
      for (int db = 0; db < 4; ++db) oacc[db][i] *= sc;
    }
#pragma unroll
    for (int mk = 1; mk <= 8; mk <<= 1)
#pragma unroll
      for (int i = 0; i < 4; ++i) rsum[i] += __shfl_xor(rsum[i], mk);
#pragma unroll
    for (int i = 0; i < 4; ++i) l_i[i] += rsum[i];
#pragma unroll
    for (int kb = 0; kb < 4; ++kb) {
      const int col = kb * 16 + c;
      const int chunk = col >> 3;
      const int lo = col & 7;
#pragma unroll
      for (int i = 0; i < 4; ++i) {
        const int row = 4 * g + i;
        P[row * 64 + ((chunk ^ (row & 7)) * 8) + lo] = f2bf(sacc[kb][i]);
      }
    }
    asm volatile("s_waitcnt lgkmcnt(0)" ::: "memory");
    bfrag8 pa[2];
#pragma unroll
    for (int ks = 0; ks < 2; ++ks) {
      const int row = c;
      const int chunk = (4 * ks + g) ^ (row & 7);
      pa[ks] = *(const bfrag8*)&P[row * 64 + chunk * 8];
    }
#pragma unroll
    for (int ks = 0; ks < 2; ++ks) {
      const float* vp = Vb + (size_t)(kv0 + ks * 32 + g * 8) * ROWSTRIDE + c;
#pragma unroll
      for (int db = 0; db < 4; ++db) {
        bfrag8 vf;
#pragma unroll
        for (int j = 0; j < 8; ++j)
          vf[j] = (short)f2bf(vp[(size_t)j * ROWSTRIDE + db * 16]);
        oacc[db] = __builtin_amdgcn_mfma_f32_16x16x32_bf16(pa[ks], vf, oacc[db], 0, 0, 0);
      }
    }
  }
#pragma unroll
  for (int i = 0; i < 4; ++i) {
    const float inv = 1.f / l_i[i];
    const int qq = qr0 + 4 * g + i;
    float* op = Ob + (size_t)qq * ROWSTRIDE + c;
#pragma unroll
    for (int db = 0; db < 4; ++db)
      op[db * 16] = oacc[db][i] * inv;
  }
}

extern "C" void kernel_launch(void* const* d_in, const int* in_sizes, int n_in,
                              void* d_out, int out_size, void* d_ws, size_t ws_size,
                              hipStream_t stream) {
  const float* Q = (const float*)d_in[0];
  const float* K = (const float*)d_in[1];
  const float* V = (const float*)d_in[2];
  float* O = (float*)d_out;

  const size_t need = 3 * NTOT * sizeof(unsigned short);
  if (ws_size >= need) {
    unsigned short* Qb = (unsigned short*)d_ws;
    unsigned short* Kb = Qb + NTOT;
    unsigned short* Vt = Kb + NTOT;
    prep_kernel<<<dim3(2048), dim3(256), 0, stream>>>(Q, K, V, Qb, Kb, Vt);
    mha_fwd_sw<<<dim3(4096), dim3(64), 0, stream>>>(Qb, Kb, Vt, O);
  } else {
    mha_fwd_f32<<<dim3(2048), dim3(256), 0, stream>>>(Q, K, V, O);
  }
}